// Round 5
// baseline (281.964 us; speedup 1.0000x reference)
//
#include <hip/hip_runtime.h>
#include <hip/hip_cooperative_groups.h>

namespace cg = cooperative_groups;

#define N_DIM 4
#define C_DIM 256
#define T_DIM 5
#define HW    784
#define L_TOK 3920   // T*H*W
#define CI    128
#define CA    128
#define NTILE 62     // ceil(L_TOK/64)

// ws layout (floats):
//   [0,      131072)  transposed weights: alignT[CA][C] | phiT[C][CI] | gT[C][CI] | WzT[CI][C]
//   [131072, 258048)  Xpart [N*NTILE][2][C]  per-block Xs partials (slot 0 = tlo, slot 1 = thi)
#define WS_TR   0
#define WS_XP   131072

struct Args {
    const float *x, *audio, *align_W, *align_b, *g_W, *g_b, *theta_W, *theta_b,
                *phi_W, *phi_b, *Wz_W, *Wz_b, *bn_gamma, *bn_beta, *bn_mean,
                *bn_var, *ln_gamma, *ln_beta;
    float *ws, *out, *out_audio;
};

// grid (62, 4) x 1024 threads = 16 channel-groups x 64 tokens per block
__global__ __launch_bounds__(1024) void kFused(Args A) {
    __shared__ float audio_s[T_DIM * CA];
    __shared__ float xs_s[T_DIM * C_DIM];
    __shared__ float at_s[T_DIM * C_DIM];
    __shared__ float phi_s[T_DIM * CI];
    __shared__ float g2_s[T_DIM * CI];
    __shared__ float TPs[T_DIM * C_DIM];
    __shared__ float GWs[T_DIM * C_DIM];
    __shared__ float tb_s[T_DIM];
    __shared__ float B_s[C_DIM], inv_s[C_DIM], lng_s[C_DIM], lnb_s[C_DIM];
    __shared__ float Fp[T_DIM * 1024];
    __shared__ float Sp[2 * 1024];

    int tile = blockIdx.x;
    int n    = blockIdx.y;
    int bid  = n * NTILE + tile;
    int tid  = threadIdx.x;
    int g    = tid >> 6;
    int li   = tid & 63;
    int l    = tile * 64 + li;
    bool act = (l < L_TOK);

    float* ws = A.ws;
    const float* alignT = ws + WS_TR;
    const float* phiT   = ws + WS_TR + 32768;
    const float* gT     = ws + WS_TR + 65536;
    const float* WzT    = ws + WS_TR + 98304;

    // ---- phase 0a: cooperative weight transpose (each thread <=1 element) ----
    {
        int gid = bid * 1024 + tid;
        if (gid < 131072) {
            int m = gid >> 15;
            int r = gid & 32767;
            float v;
            if (m == 0)      { int a = r >> 8, c = r & 255; v = A.align_W[c * CA + a]; }
            else if (m == 1) { int c = r >> 7, o = r & 127; v = A.phi_W[o * C_DIM + c]; }
            else if (m == 2) { int c = r >> 7, o = r & 127; v = A.g_W[o * C_DIM + c]; }
            else             { int o = r >> 8, c = r & 255; v = A.Wz_W[c * CI + o]; }
            ws[WS_TR + gid] = v;
        }
    }

    // ---- phase 0: stage per-n constants ----
    if (tid < T_DIM * CA) audio_s[tid] = A.audio[n * T_DIM * CA + tid];
    if (tid < C_DIM) {
        int c = tid;
        float inv = A.bn_gamma[c] * rsqrtf(A.bn_var[c] + 1e-5f);
        inv_s[c] = inv * (1.0f / (float)L_TOK);
        B_s[c]   = (A.Wz_b[c] - A.bn_mean[c]) * inv + A.bn_beta[c];
        lng_s[c] = A.ln_gamma[c];
        lnb_s[c] = A.ln_beta[c];
    }

    // ---- phase 0b: load x tile into registers; per-block Xs partials ----
    float xz[16];
    const float* xb = A.x + ((size_t)(n * C_DIM + g * 16)) * L_TOK + l;
    #pragma unroll
    for (int j = 0; j < 16; ++j) xz[j] = act ? xb[(size_t)j * L_TOK] : 0.f;

    {
        int base = tile * 64;
        int tlo  = base / HW;
        int thi  = ((base + 63 < L_TOK) ? (base + 63) : (L_TOK - 1)) / HW;
        int myl  = act ? l : (L_TOK - 1);
        int mytt = myl / HW;
        bool straddle = (thi != tlo);           // wave-uniform
        float* xp = ws + WS_XP + bid * 512;
        #pragma unroll
        for (int j = 0; j < 16; ++j) {
            float tot = xz[j];
            for (int off = 32; off > 0; off >>= 1) tot += __shfl_down(tot, off, 64);
            if (!straddle) {
                if (li == 0) xp[g * 16 + j] = tot;
            } else {
                float v0 = (mytt == tlo) ? xz[j] : 0.f;
                for (int off = 32; off > 0; off >>= 1) v0 += __shfl_down(v0, off, 64);
                if (li == 0) {
                    xp[g * 16 + j]       = v0;
                    xp[256 + g * 16 + j] = tot - v0;
                }
            }
        }
    }
    __threadfence();
    cg::this_grid().sync();

    // ---- phase 1: gather Xs[n][t][c] from partials ----
    for (int i = tid; i < T_DIM * C_DIM; i += 1024) {
        int t = i >> 8, c = i & 255;
        float s = 0.f;
        for (int tt = 0; tt < NTILE; ++tt) {
            int b2 = tt * 64;
            int tl = b2 / HW;
            int th = ((b2 + 63 < L_TOK) ? (b2 + 63) : (L_TOK - 1)) / HW;
            const float* q = ws + WS_XP + (n * NTILE + tt) * 512;
            if (t == tl)      s += q[c];
            else if (t == th) s += q[256 + c];
        }
        xs_s[i] = s;
    }

    // ---- B1: at[t][c] = audio[t,:] . align_W[c,:] + align_b[c] ----
    for (int i = tid; i < T_DIM * C_DIM; i += 1024) {
        int t = i >> 8, c = i & 255;
        float a0 = 0, a1 = 0, a2 = 0, a3 = 0;
        const float* as = audio_s + t * CA;
        #pragma unroll 8
        for (int a = 0; a < CA; a += 4) {
            a0 = fmaf(alignT[(a + 0) * C_DIM + c], as[a + 0], a0);
            a1 = fmaf(alignT[(a + 1) * C_DIM + c], as[a + 1], a1);
            a2 = fmaf(alignT[(a + 2) * C_DIM + c], as[a + 2], a2);
            a3 = fmaf(alignT[(a + 3) * C_DIM + c], as[a + 3], a3);
        }
        float v = A.align_b[c] + (a0 + a1) + (a2 + a3);
        at_s[i] = v;
        if (tile == 0) A.out_audio[n * T_DIM * C_DIM + i] = v;
    }
    __syncthreads();

    // ---- B2: phi[t][o], G[t][o] ----
    if (tid < T_DIM * CI) {
        int t = tid >> 7, o = tid & 127;
        const float* ats = at_s + t * C_DIM;
        const float* xss = xs_s + t * C_DIM;
        float p0 = 0, p1 = 0, q0 = 0, q1 = 0;
        #pragma unroll 8
        for (int c = 0; c < C_DIM; c += 2) {
            p0 = fmaf(phiT[(c + 0) * CI + o], ats[c + 0], p0);
            p1 = fmaf(phiT[(c + 1) * CI + o], ats[c + 1], p1);
            q0 = fmaf(gT[(c + 0) * CI + o],  xss[c + 0], q0);
            q1 = fmaf(gT[(c + 1) * CI + o],  xss[c + 1], q1);
        }
        phi_s[tid] = A.phi_b[o] + p0 + p1;
        g2_s[tid]  = (float)HW * A.g_b[o] + q0 + q1;
    }
    __syncthreads();

    // ---- B3: TP[t][c], GW[t][c], tb[t] ----
    for (int i = tid; i < T_DIM * C_DIM; i += 1024) {
        int t = i >> 8, c = i & 255;
        const float* ps = phi_s + t * CI;
        const float* gs = g2_s + t * CI;
        float a0 = 0, a1 = 0, b0 = 0, b1 = 0;
        #pragma unroll 8
        for (int o = 0; o < CI; o += 2) {
            a0 = fmaf(A.theta_W[(o + 0) * C_DIM + c], ps[o + 0], a0);
            a1 = fmaf(A.theta_W[(o + 1) * C_DIM + c], ps[o + 1], a1);
            b0 = fmaf(WzT[(o + 0) * C_DIM + c],       gs[o + 0], b0);
            b1 = fmaf(WzT[(o + 1) * C_DIM + c],       gs[o + 1], b1);
        }
        TPs[i] = a0 + a1;
        GWs[i] = (b0 + b1) * inv_s[c];
    }
    if (tid < T_DIM * 64) {
        int t = tid >> 6, lane = tid & 63;
        float p = A.theta_b[lane] * phi_s[t * CI + lane] +
                  A.theta_b[lane + 64] * phi_s[t * CI + lane + 64];
        for (int off = 32; off > 0; off >>= 1) p += __shfl_down(p, off, 64);
        if (lane == 0) tb_s[t] = p;
    }
    __syncthreads();

    // ---- B4: F[t] partials from registers ----
    float F0 = 0, F1 = 0, F2 = 0, F3 = 0, F4 = 0;
    #pragma unroll
    for (int j = 0; j < 16; ++j) {
        const float* tp = TPs + g * 16 + j;
        F0 = fmaf(xz[j], tp[0],    F0);
        F1 = fmaf(xz[j], tp[256],  F1);
        F2 = fmaf(xz[j], tp[512],  F2);
        F3 = fmaf(xz[j], tp[768],  F3);
        F4 = fmaf(xz[j], tp[1024], F4);
    }
    Fp[0 * 1024 + tid] = F0; Fp[1 * 1024 + tid] = F1; Fp[2 * 1024 + tid] = F2;
    Fp[3 * 1024 + tid] = F3; Fp[4 * 1024 + tid] = F4;
    __syncthreads();

    // ---- B5: full F per token, z over own channels, stats ----
    float Ft[T_DIM];
    #pragma unroll
    for (int t = 0; t < T_DIM; ++t) {
        float a = tb_s[t];
        #pragma unroll
        for (int w = 0; w < 16; ++w) a += Fp[t * 1024 + w * 64 + li];
        Ft[t] = a;
    }
    float s1 = 0.f, s2 = 0.f;
    #pragma unroll
    for (int j = 0; j < 16; ++j) {
        int c = g * 16 + j;
        float zc = B_s[c] + xz[j];
        zc = fmaf(Ft[0], GWs[c],        zc);
        zc = fmaf(Ft[1], GWs[256 + c],  zc);
        zc = fmaf(Ft[2], GWs[512 + c],  zc);
        zc = fmaf(Ft[3], GWs[768 + c],  zc);
        zc = fmaf(Ft[4], GWs[1024 + c], zc);
        xz[j] = zc;
        s1 += zc;
        s2 = fmaf(zc, zc, s2);
    }
    Sp[tid]        = s1;
    Sp[1024 + tid] = s2;
    __syncthreads();

    // ---- B6: LayerNorm over channels, write out ----
    float t1 = 0.f, t2 = 0.f;
    #pragma unroll
    for (int w = 0; w < 16; ++w) {
        t1 += Sp[w * 64 + li];
        t2 += Sp[1024 + w * 64 + li];
    }
    float mu   = t1 * (1.0f / C_DIM);
    float var  = t2 * (1.0f / C_DIM) - mu * mu;
    float rstd = rsqrtf(var + 1e-5f);
    if (act) {
        float* ob = A.out + ((size_t)(n * C_DIM + g * 16)) * L_TOK + l;
        #pragma unroll
        for (int j = 0; j < 16; ++j) {
            int c = g * 16 + j;
            ob[(size_t)j * L_TOK] = fmaf((xz[j] - mu) * rstd, lng_s[c], lnb_s[c]);
        }
    }
}

extern "C" void kernel_launch(void* const* d_in, const int* in_sizes, int n_in,
                              void* d_out, int out_size, void* d_ws, size_t ws_size,
                              hipStream_t stream) {
    Args ha;
    ha.x        = (const float*)d_in[0];
    ha.audio    = (const float*)d_in[1];
    ha.align_W  = (const float*)d_in[2];
    ha.align_b  = (const float*)d_in[3];
    ha.g_W      = (const float*)d_in[4];
    ha.g_b      = (const float*)d_in[5];
    ha.theta_W  = (const float*)d_in[6];
    ha.theta_b  = (const float*)d_in[7];
    ha.phi_W    = (const float*)d_in[8];
    ha.phi_b    = (const float*)d_in[9];
    ha.Wz_W     = (const float*)d_in[10];
    ha.Wz_b     = (const float*)d_in[11];
    ha.bn_gamma = (const float*)d_in[12];
    ha.bn_beta  = (const float*)d_in[13];
    ha.bn_mean  = (const float*)d_in[14];
    ha.bn_var   = (const float*)d_in[15];
    ha.ln_gamma = (const float*)d_in[16];
    ha.ln_beta  = (const float*)d_in[17];
    ha.ws        = (float*)d_ws;
    ha.out       = (float*)d_out;
    ha.out_audio = (float*)d_out + (size_t)N_DIM * C_DIM * L_TOK;

    void* kargs[] = { (void*)&ha };
    hipLaunchCooperativeKernel((const void*)kFused, dim3(NTILE, N_DIM, 1),
                               dim3(1024, 1, 1), kargs, 0, stream);
}

// Round 6
// 135.329 us; speedup vs baseline: 2.0835x; 2.0835x over previous
//
#include <hip/hip_runtime.h>

#define N_DIM 4
#define C_DIM 256
#define T_DIM 5
#define HW    784
#define L_TOK 3920   // T*H*W
#define CI    128
#define CA    128

// ws layout (floats):
//   [0,     5120)  Xs [N][T][C]
//   [5120, 10240)  at [N][T][C]   (audio_temp)
//   [10240,15360)  TP [N][T][C]
//   [15360,20480)  GW [N][T][C]   (Wz_W @ G * bn_inv / L folded)
//   [20480,20500)  tb [N][T]
#define WS_XS  0
#define WS_AT  5120
#define WS_TP  10240
#define WS_GW  15360
#define WS_TB  20480

// ---------------- kernel 1: Xs reduction + audio_temp (independent halves) ----------------
// blocks [0,5120): Xs[n,t,c] = sum_{h,w} x[n,c,t,h,w]
// blocks [5120,5140): at[nt,c] = audio[nt,:] . align_W[c,:] + align_b[c]
__global__ __launch_bounds__(256) void k1(const float* __restrict__ x,
                                          const float* __restrict__ audio,
                                          const float* __restrict__ align_W,
                                          const float* __restrict__ align_b,
                                          float* __restrict__ ws,
                                          float* __restrict__ out_audio) {
    int bid = blockIdx.x;
    int tid = threadIdx.x;
    if (bid < N_DIM * C_DIM * T_DIM) {
        int n   = bid / (C_DIM * T_DIM);
        int rem = bid % (C_DIM * T_DIM);
        int c   = rem / T_DIM;
        int t   = rem % T_DIM;
        const float4* base = (const float4*)(x + ((size_t)(n * C_DIM + c) * T_DIM + t) * HW);
        float p = 0.f;
        if (tid < HW / 4) {
            float4 v = base[tid];
            p = (v.x + v.y) + (v.z + v.w);
        }
        for (int off = 32; off > 0; off >>= 1) p += __shfl_down(p, off, 64);
        __shared__ float wsum[4];
        if ((tid & 63) == 0) wsum[tid >> 6] = p;
        __syncthreads();
        if (tid == 0)
            ws[WS_XS + (n * T_DIM + t) * C_DIM + c] = wsum[0] + wsum[1] + wsum[2] + wsum[3];
    } else {
        int nt = bid - N_DIM * C_DIM * T_DIM;     // 0..19
        __shared__ float audio_s[CA];
        if (tid < CA) audio_s[tid] = audio[nt * CA + tid];
        __syncthreads();
        const float4* row = (const float4*)(align_W + tid * CA);
        float a0 = 0, a1 = 0, a2 = 0, a3 = 0;
        #pragma unroll
        for (int k = 0; k < CA / 4; ++k) {
            float4 w = row[k];
            a0 = fmaf(w.x, audio_s[4 * k + 0], a0);
            a1 = fmaf(w.y, audio_s[4 * k + 1], a1);
            a2 = fmaf(w.z, audio_s[4 * k + 2], a2);
            a3 = fmaf(w.w, audio_s[4 * k + 3], a3);
        }
        float acc = align_b[tid] + (a0 + a1) + (a2 + a3);
        ws[WS_AT + nt * C_DIM + tid] = acc;
        out_audio[nt * C_DIM + tid] = acc;        // 2nd tuple output
    }
}

// ------------- kernel 2: per-(n,t) chain, lane-split dots, 1024 threads -------------
__global__ __launch_bounds__(1024) void k2(
    const float* __restrict__ g_W,     const float* __restrict__ g_b,
    const float* __restrict__ theta_W, const float* __restrict__ theta_b,
    const float* __restrict__ phi_W,   const float* __restrict__ phi_b,
    const float* __restrict__ Wz_W,    const float* __restrict__ bn_gamma,
    const float* __restrict__ bn_var,  float* __restrict__ ws) {
    int nt  = blockIdx.x;                 // n*T + t
    int tid = threadIdx.x;

    __shared__ float at_s[C_DIM];
    __shared__ float xs_s[C_DIM];
    __shared__ float phi_s[CI];
    __shared__ float g_s[CI];

    if (tid < C_DIM) at_s[tid] = ws[WS_AT + nt * C_DIM + tid];
    else if (tid < 2 * C_DIM) xs_s[tid - C_DIM] = ws[WS_XS + nt * C_DIM + (tid - C_DIM)];
    __syncthreads();

    // ---- phase A: phi[o] (tid<512), G[o] (tid>=512); 4 lanes per output, 64 terms each ----
    {
        int half = tid >> 9;              // 0: phi, 1: G
        int o    = (tid >> 2) & 127;
        int s    = tid & 3;
        const float* wrow = (half == 0 ? phi_W : g_W) + o * C_DIM + s * 64;
        const float* vec  = (half == 0 ? at_s : xs_s) + s * 64;
        float v0 = 0, v1 = 0;
        #pragma unroll
        for (int i = 0; i < 64; i += 2) {
            v0 = fmaf(wrow[i + 0], vec[i + 0], v0);
            v1 = fmaf(wrow[i + 1], vec[i + 1], v1);
        }
        float v = v0 + v1;
        v += __shfl_xor(v, 1, 64);
        v += __shfl_xor(v, 2, 64);
        if (s == 0) {
            if (half == 0) phi_s[o] = phi_b[o] + v;
            else           g_s[o]   = (float)HW * g_b[o] + v;
        }
    }
    __syncthreads();

    // ---- phase B: TP[c] (tid<512), GW[c] (tid>=512); 2 lanes per output, 64 terms each ----
    {
        int half = tid >> 9;              // 0: TP, 1: GW
        int c    = (tid >> 1) & 255;
        int s    = tid & 1;
        float v0 = 0, v1 = 0;
        if (half == 0) {
            const float* ps = phi_s + s * 64;
            #pragma unroll
            for (int i = 0; i < 64; i += 2) {
                v0 = fmaf(theta_W[(s * 64 + i + 0) * C_DIM + c], ps[i + 0], v0);
                v1 = fmaf(theta_W[(s * 64 + i + 1) * C_DIM + c], ps[i + 1], v1);
            }
        } else {
            const float* wr = Wz_W + c * CI + s * 64;
            const float* gs = g_s + s * 64;
            #pragma unroll
            for (int i = 0; i < 64; i += 2) {
                v0 = fmaf(wr[i + 0], gs[i + 0], v0);
                v1 = fmaf(wr[i + 1], gs[i + 1], v1);
            }
        }
        float v = v0 + v1;
        v += __shfl_xor(v, 1, 64);
        if (s == 0) {
            if (half == 0) {
                ws[WS_TP + nt * C_DIM + c] = v;
            } else {
                float inv = bn_gamma[c] * rsqrtf(bn_var[c] + 1e-5f);
                ws[WS_GW + nt * C_DIM + c] = v * inv * (1.0f / (float)L_TOK);
            }
        }
    }
    // ---- phase C: tb = theta_b . phi ----
    __syncthreads();
    if (tid < 64) {
        float p = theta_b[tid] * phi_s[tid] + theta_b[tid + 64] * phi_s[tid + 64];
        for (int off = 32; off > 0; off >>= 1) p += __shfl_down(p, off, 64);
        if (tid == 0) ws[WS_TB + nt] = p;
    }
}

// ------------- kernel 3: fused F + epilogue + residual + LayerNorm (round-2 best) -------------
// block: 1024 thr = 16 groups x 64 tokens; x/z tile lives in 16 regs/thread.
__global__ __launch_bounds__(1024) void k3_main(
    const float* __restrict__ x,        const float* __restrict__ ws,
    const float* __restrict__ Wz_b,     const float* __restrict__ bn_gamma,
    const float* __restrict__ bn_beta,  const float* __restrict__ bn_mean,
    const float* __restrict__ bn_var,   const float* __restrict__ ln_gamma,
    const float* __restrict__ ln_beta,  float* __restrict__ out) {
    __shared__ float TPs[T_DIM * C_DIM];
    __shared__ float GWs[T_DIM * C_DIM];
    __shared__ float tb_s[T_DIM];
    __shared__ float B_s[C_DIM], lng_s[C_DIM], lnb_s[C_DIM];
    __shared__ float Fp[T_DIM * 1024];     // [t][group][token]
    __shared__ float Sp[2 * 1024];         // [2][group][token]

    int n    = blockIdx.y;
    int tile = blockIdx.x;
    int tid  = threadIdx.x;
    int g    = tid >> 6;        // channel group 0..15 (== wave id)
    int li   = tid & 63;        // token within tile
    int l    = tile * 64 + li;
    bool act = (l < L_TOK);

    for (int i = tid; i < T_DIM * C_DIM; i += 1024) {
        TPs[i] = ws[WS_TP + n * T_DIM * C_DIM + i];
        GWs[i] = ws[WS_GW + n * T_DIM * C_DIM + i];
    }
    if (tid < T_DIM) tb_s[tid] = ws[WS_TB + n * T_DIM + tid];
    if (tid < C_DIM) {
        int c = tid;
        float inv = bn_gamma[c] * rsqrtf(bn_var[c] + 1e-5f);
        B_s[c]   = (Wz_b[c] - bn_mean[c]) * inv + bn_beta[c];
        lng_s[c] = ln_gamma[c];
        lnb_s[c] = ln_beta[c];
    }
    __syncthreads();

    // phase 1: load 16 channels of token l into regs; F[t] partials
    float xz[16];
    const float* xb = x + ((size_t)(n * C_DIM + g * 16)) * L_TOK + l;
    #pragma unroll
    for (int j = 0; j < 16; ++j) xz[j] = act ? xb[(size_t)j * L_TOK] : 0.f;

    float F0 = 0, F1 = 0, F2 = 0, F3 = 0, F4 = 0;
    #pragma unroll
    for (int j = 0; j < 16; ++j) {
        const float* tp = TPs + g * 16 + j;
        F0 = fmaf(xz[j], tp[0],    F0);
        F1 = fmaf(xz[j], tp[256],  F1);
        F2 = fmaf(xz[j], tp[512],  F2);
        F3 = fmaf(xz[j], tp[768],  F3);
        F4 = fmaf(xz[j], tp[1024], F4);
    }
    Fp[0 * 1024 + tid] = F0; Fp[1 * 1024 + tid] = F1; Fp[2 * 1024 + tid] = F2;
    Fp[3 * 1024 + tid] = F3; Fp[4 * 1024 + tid] = F4;
    __syncthreads();

    // phase 2: full F per token (sum over 16 groups), z over own channels, stats
    float Ft[T_DIM];
    #pragma unroll
    for (int t = 0; t < T_DIM; ++t) {
        float a = tb_s[t];
        #pragma unroll
        for (int w = 0; w < 16; ++w) a += Fp[t * 1024 + w * 64 + li];
        Ft[t] = a;
    }
    float s1 = 0.f, s2 = 0.f;
    #pragma unroll
    for (int j = 0; j < 16; ++j) {
        int c = g * 16 + j;
        float zc = B_s[c] + xz[j];
        zc = fmaf(Ft[0], GWs[c],        zc);
        zc = fmaf(Ft[1], GWs[256 + c],  zc);
        zc = fmaf(Ft[2], GWs[512 + c],  zc);
        zc = fmaf(Ft[3], GWs[768 + c],  zc);
        zc = fmaf(Ft[4], GWs[1024 + c], zc);
        xz[j] = zc;
        s1 += zc;
        s2 = fmaf(zc, zc, s2);
    }
    Sp[tid]        = s1;
    Sp[1024 + tid] = s2;
    __syncthreads();

    // phase 3: LayerNorm over channels, write out
    float t1 = 0.f, t2 = 0.f;
    #pragma unroll
    for (int w = 0; w < 16; ++w) {
        t1 += Sp[w * 64 + li];
        t2 += Sp[1024 + w * 64 + li];
    }
    float mu   = t1 * (1.0f / C_DIM);
    float var  = t2 * (1.0f / C_DIM) - mu * mu;
    float rstd = rsqrtf(var + 1e-5f);
    if (act) {
        float* ob = out + ((size_t)(n * C_DIM + g * 16)) * L_TOK + l;
        #pragma unroll
        for (int j = 0; j < 16; ++j) {
            int c = g * 16 + j;
            ob[(size_t)j * L_TOK] = fmaf((xz[j] - mu) * rstd, lng_s[c], lnb_s[c]);
        }
    }
}

extern "C" void kernel_launch(void* const* d_in, const int* in_sizes, int n_in,
                              void* d_out, int out_size, void* d_ws, size_t ws_size,
                              hipStream_t stream) {
    const float* x        = (const float*)d_in[0];
    const float* audio    = (const float*)d_in[1];
    const float* align_W  = (const float*)d_in[2];
    const float* align_b  = (const float*)d_in[3];
    const float* g_W      = (const float*)d_in[4];
    const float* g_b      = (const float*)d_in[5];
    const float* theta_W  = (const float*)d_in[6];
    const float* theta_b  = (const float*)d_in[7];
    const float* phi_W    = (const float*)d_in[8];
    const float* phi_b    = (const float*)d_in[9];
    const float* Wz_W     = (const float*)d_in[10];
    const float* Wz_b     = (const float*)d_in[11];
    const float* bn_gamma = (const float*)d_in[12];
    const float* bn_beta  = (const float*)d_in[13];
    const float* bn_mean  = (const float*)d_in[14];
    const float* bn_var   = (const float*)d_in[15];
    const float* ln_gamma = (const float*)d_in[16];
    const float* ln_beta  = (const float*)d_in[17];

    float* out       = (float*)d_out;
    float* out_audio = out + (size_t)N_DIM * C_DIM * L_TOK;   // 4,014,080
    float* ws        = (float*)d_ws;

    k1<<<N_DIM * C_DIM * T_DIM + N_DIM * T_DIM, 256, 0, stream>>>(
        x, audio, align_W, align_b, ws, out_audio);
    k2<<<N_DIM * T_DIM, 1024, 0, stream>>>(
        g_W, g_b, theta_W, theta_b, phi_W, phi_b, Wz_W, bn_gamma, bn_var, ws);
    dim3 grid3((L_TOK + 63) / 64, N_DIM);
    k3_main<<<grid3, 1024, 0, stream>>>(
        x, ws, Wz_b, bn_gamma, bn_beta, bn_mean, bn_var, ln_gamma, ln_beta, out);
}